// Round 1
// baseline (1172.459 us; speedup 1.0000x reference)
//
#include <hip/hip_runtime.h>
#include <cmath>

#define TS 64
#define LSTR 132
#define ATTN_SCALE 0.25f

// ---------- small utility kernels ----------

__global__ __launch_bounds__(256) void transpose_k(const float* __restrict__ s,
                                                   float* __restrict__ d, int R, int C) {
    int idx = blockIdx.x * 256 + threadIdx.x;
    if (idx < R * C) {
        int r = idx / C, c = idx % C;
        d[c * R + r] = s[idx];
    }
}

__global__ __launch_bounds__(256) void hist_kernel(const int* __restrict__ dst,
                                                   int* __restrict__ counts, int E) {
    int i = blockIdx.x * 256 + threadIdx.x;
    if (i < E) atomicAdd(&counts[dst[i]], 1);
}

__global__ __launch_bounds__(1024) void scan_kernel(const int* __restrict__ counts,
                                                    int* __restrict__ offsets, int N) {
    __shared__ int buf[1024];
    __shared__ int carry;
    int t = threadIdx.x;
    if (t == 0) { carry = 0; offsets[0] = 0; }
    __syncthreads();
    for (int base = 0; base < N; base += 1024) {
        int i = base + t;
        int v = (i < N) ? counts[i] : 0;
        buf[t] = v;
        __syncthreads();
        for (int dshift = 1; dshift < 1024; dshift <<= 1) {
            int add = (t >= dshift) ? buf[t - dshift] : 0;
            __syncthreads();
            buf[t] += add;
            __syncthreads();
        }
        if (i < N) offsets[i + 1] = carry + buf[t];
        __syncthreads();
        if (t == 0) carry += buf[1023];
        __syncthreads();
    }
}

__global__ __launch_bounds__(256) void copy_kernel(const int* __restrict__ a,
                                                   int* __restrict__ b, int n) {
    int i = blockIdx.x * 256 + threadIdx.x;
    if (i < n) b[i] = a[i];
}

__global__ __launch_bounds__(256) void scatter_kernel(const int* __restrict__ dst,
                                                      int* __restrict__ cursor,
                                                      int* __restrict__ eidx, int E) {
    int i = blockIdx.x * 256 + threadIdx.x;
    if (i < E) {
        int p = atomicAdd(&cursor[dst[i]], 1);
        eidx[p] = i;
    }
}

// ---------- qkv projection: q,k,v = h @ qkv_w.T + b ----------
// wT is qkv_w transposed: wT[k*384 + r], r in [0,384)

__global__ __launch_bounds__(256) void qkv_kernel(
    const float* __restrict__ h, const float* __restrict__ wT,
    const float* __restrict__ qkvb, float* __restrict__ qb,
    float* __restrict__ kb, float* __restrict__ vb, int N)
{
    __shared__ float tile[TS * LSTR];
    const int t = threadIdx.x;
    const int base = blockIdx.x * TS;
    for (int i = 0; i < 8; ++i) {
        int flat = i * 1024 + t * 4;
        int r = flat >> 7, k = flat & 127;
        float4 val = make_float4(0.f, 0.f, 0.f, 0.f);
        if (base + r < N) val = *reinterpret_cast<const float4*>(&h[(size_t)(base + r) * 128 + k]);
        *reinterpret_cast<float4*>(&tile[r * LSTR + k]) = val;
    }
    __syncthreads();
    const int tx = t & 15, ty = t >> 4;
    const int col = tx * 8, row0 = ty * 4;
    for (int ch = 0; ch < 3; ++ch) {
        float acc[4][8];
        #pragma unroll
        for (int i = 0; i < 4; ++i)
            #pragma unroll
            for (int j = 0; j < 8; ++j) acc[i][j] = 0.f;
        const float* wp = wT + ch * 128 + col;
        #pragma unroll 4
        for (int k = 0; k < 128; ++k) {
            float4 w0 = *reinterpret_cast<const float4*>(&wp[k * 384]);
            float4 w1 = *reinterpret_cast<const float4*>(&wp[k * 384 + 4]);
            float wv[8] = {w0.x, w0.y, w0.z, w0.w, w1.x, w1.y, w1.z, w1.w};
            float ev[4];
            #pragma unroll
            for (int i = 0; i < 4; ++i) ev[i] = tile[(row0 + i) * LSTR + k];
            #pragma unroll
            for (int i = 0; i < 4; ++i)
                #pragma unroll
                for (int j = 0; j < 8; ++j) acc[i][j] += ev[i] * wv[j];
        }
        float* out = (ch == 0) ? qb : (ch == 1) ? kb : vb;
        float4 b0 = *reinterpret_cast<const float4*>(&qkvb[ch * 128 + col]);
        float4 b1 = *reinterpret_cast<const float4*>(&qkvb[ch * 128 + col + 4]);
        #pragma unroll
        for (int i = 0; i < 4; ++i) {
            int r = base + row0 + i;
            if (r < N) {
                float4 o0 = make_float4(acc[i][0] + b0.x, acc[i][1] + b0.y,
                                        acc[i][2] + b0.z, acc[i][3] + b0.w);
                float4 o1 = make_float4(acc[i][4] + b1.x, acc[i][5] + b1.y,
                                        acc[i][6] + b1.z, acc[i][7] + b1.w);
                *reinterpret_cast<float4*>(&out[(size_t)r * 128 + col]) = o0;
                *reinterpret_cast<float4*>(&out[(size_t)r * 128 + col + 4]) = o1;
            }
        }
    }
}

// ---------- fused edge kernel: c -> score -> {logit, mean, e_out} ----------
// cT[k*128+c] = c_w[c][k];  eT[k*128+c] = eproj_w[c][k]

__global__ __launch_bounds__(256) void edge_kernel(
    const float* __restrict__ e, const int* __restrict__ src, const int* __restrict__ dst,
    const float* __restrict__ cT, const float* __restrict__ cbias,
    const float* __restrict__ eT, const float* __restrict__ ebias,
    const float* __restrict__ qb, const float* __restrict__ kb,
    float* __restrict__ e_out, float* __restrict__ mean_out,
    float* __restrict__ logit, int E)
{
    __shared__ float tile[TS * LSTR];
    const int t = threadIdx.x;
    const int base = blockIdx.x * TS;
    for (int i = 0; i < 8; ++i) {
        int flat = i * 1024 + t * 4;
        int r = flat >> 7, k = flat & 127;
        float4 val = make_float4(0.f, 0.f, 0.f, 0.f);
        if (base + r < E) val = *reinterpret_cast<const float4*>(&e[(size_t)(base + r) * 128 + k]);
        *reinterpret_cast<float4*>(&tile[r * LSTR + k]) = val;
    }
    __syncthreads();
    const int tx = t & 15, ty = t >> 4;
    const int col = tx * 8, row0 = ty * 4;

    float acc[4][8];
    #pragma unroll
    for (int i = 0; i < 4; ++i)
        #pragma unroll
        for (int j = 0; j < 8; ++j) acc[i][j] = 0.f;

    // GEMM1: e @ c_w.T
    #pragma unroll 4
    for (int k = 0; k < 128; ++k) {
        float4 w0 = *reinterpret_cast<const float4*>(&cT[k * 128 + col]);
        float4 w1 = *reinterpret_cast<const float4*>(&cT[k * 128 + col + 4]);
        float wv[8] = {w0.x, w0.y, w0.z, w0.w, w1.x, w1.y, w1.z, w1.w};
        float ev[4];
        #pragma unroll
        for (int i = 0; i < 4; ++i) ev[i] = tile[(row0 + i) * LSTR + k];
        #pragma unroll
        for (int i = 0; i < 4; ++i)
            #pragma unroll
            for (int j = 0; j < 8; ++j) acc[i][j] += ev[i] * wv[j];
    }

    float cbv[8];
    #pragma unroll
    for (int j = 0; j < 8; ++j) cbv[j] = cbias[col + j];

    int edges[4];
    bool val4[4];
    // tanh -> score = c * k[src] * q[dst]
    #pragma unroll
    for (int i = 0; i < 4; ++i) {
        int edge = base + row0 + i;
        bool valid = edge < E;
        edges[i] = edge; val4[i] = valid;
        int si = valid ? src[edge] : 0;
        int di = valid ? dst[edge] : 0;
        float4 k0 = *reinterpret_cast<const float4*>(&kb[(size_t)si * 128 + col]);
        float4 k1 = *reinterpret_cast<const float4*>(&kb[(size_t)si * 128 + col + 4]);
        float4 q0 = *reinterpret_cast<const float4*>(&qb[(size_t)di * 128 + col]);
        float4 q1 = *reinterpret_cast<const float4*>(&qb[(size_t)di * 128 + col + 4]);
        float kvv[8] = {k0.x, k0.y, k0.z, k0.w, k1.x, k1.y, k1.z, k1.w};
        float qvv[8] = {q0.x, q0.y, q0.z, q0.w, q1.x, q1.y, q1.z, q1.w};
        #pragma unroll
        for (int j = 0; j < 8; ++j) {
            float cc = tanhf(acc[i][j] + cbv[j]);
            acc[i][j] = cc * kvv[j] * qvv[j];
        }
    }

    // logit[edge][head]: each thread's 8 cols are within one head (tx>>1)
    #pragma unroll
    for (int i = 0; i < 4; ++i) {
        float p = 0.f;
        #pragma unroll
        for (int j = 0; j < 8; ++j) p += acc[i][j];
        p += __shfl_xor(p, 1);
        if ((tx & 1) == 0 && val4[i]) logit[(size_t)edges[i] * 8 + (tx >> 1)] = p * ATTN_SCALE;
    }

    // score mean over heads: d16 = (tx&1)*8 + j, reduce over tx bits 1..3
    #pragma unroll
    for (int i = 0; i < 4; ++i) {
        #pragma unroll
        for (int j = 0; j < 8; ++j) {
            float r = acc[i][j];
            r += __shfl_xor(r, 2);
            r += __shfl_xor(r, 4);
            r += __shfl_xor(r, 8);
            if (tx < 2 && val4[i]) mean_out[(size_t)edges[i] * 16 + tx * 8 + j] = r * 0.125f;
        }
    }

    __syncthreads();
    // reuse LDS for score tile
    #pragma unroll
    for (int i = 0; i < 4; ++i)
        #pragma unroll
        for (int j = 0; j < 8; ++j) tile[(row0 + i) * LSTR + col + j] = acc[i][j];
    __syncthreads();

    // GEMM2: score @ eproj_w.T
    float acc2[4][8];
    #pragma unroll
    for (int i = 0; i < 4; ++i)
        #pragma unroll
        for (int j = 0; j < 8; ++j) acc2[i][j] = 0.f;
    #pragma unroll 4
    for (int k = 0; k < 128; ++k) {
        float4 w0 = *reinterpret_cast<const float4*>(&eT[k * 128 + col]);
        float4 w1 = *reinterpret_cast<const float4*>(&eT[k * 128 + col + 4]);
        float wv[8] = {w0.x, w0.y, w0.z, w0.w, w1.x, w1.y, w1.z, w1.w};
        float sv[4];
        #pragma unroll
        for (int i = 0; i < 4; ++i) sv[i] = tile[(row0 + i) * LSTR + k];
        #pragma unroll
        for (int i = 0; i < 4; ++i)
            #pragma unroll
            for (int j = 0; j < 8; ++j) acc2[i][j] += sv[i] * wv[j];
    }
    float4 b0 = *reinterpret_cast<const float4*>(&ebias[col]);
    float4 b1 = *reinterpret_cast<const float4*>(&ebias[col + 4]);
    #pragma unroll
    for (int i = 0; i < 4; ++i) {
        if (val4[i]) {
            float4 o0 = make_float4(acc2[i][0] + b0.x, acc2[i][1] + b0.y,
                                    acc2[i][2] + b0.z, acc2[i][3] + b0.w);
            float4 o1 = make_float4(acc2[i][4] + b1.x, acc2[i][5] + b1.y,
                                    acc2[i][6] + b1.z, acc2[i][7] + b1.w);
            *reinterpret_cast<float4*>(&e_out[(size_t)edges[i] * 128 + col]) = o0;
            *reinterpret_cast<float4*>(&e_out[(size_t)edges[i] * 128 + col + 4]) = o1;
        }
    }
}

// ---------- per-node softmax + aggregation + hproj ----------
// hpT[d*128+o] = hproj_w[o][d]

__global__ __launch_bounds__(256) void node_kernel(
    const int* __restrict__ offsets, const int* __restrict__ eidx,
    const int* __restrict__ src, const float* __restrict__ logit,
    const float* __restrict__ vb, const float* __restrict__ hpT,
    const float* __restrict__ hb, float* __restrict__ h_out, int N)
{
    __shared__ float hagg[4][128];
    const int t = threadIdx.x;
    const int w = t >> 6, lane = t & 63;
    const int node = blockIdx.x * 4 + w;
    const bool valid = node < N;
    int off = 0, deg = 0;
    if (valid) { off = offsets[node]; deg = offsets[node + 1] - off; }

    const int head = lane & 7, g = lane >> 3;
    float mym = -3.0e38f;
    for (int j = g; j < deg; j += 8) {
        int eid = eidx[off + j];
        mym = fmaxf(mym, logit[(size_t)eid * 8 + head]);
    }
    mym = fmaxf(mym, __shfl_xor(mym, 8));
    mym = fmaxf(mym, __shfl_xor(mym, 16));
    mym = fmaxf(mym, __shfl_xor(mym, 32));
    float ss = 0.f;
    for (int j = g; j < deg; j += 8) {
        int eid = eidx[off + j];
        ss += __expf(logit[(size_t)eid * 8 + head] - mym);
    }
    ss += __shfl_xor(ss, 8);
    ss += __shfl_xor(ss, 16);
    ss += __shfl_xor(ss, 32);

    const int d0 = lane, d1 = lane + 64;
    const int h0 = lane >> 4, h1 = 4 + h0;
    float m0 = __shfl(mym, h0), m1 = __shfl(mym, h1);
    float s0 = __shfl(ss, h0), s1 = __shfl(ss, h1);
    float is0 = (deg > 0) ? 1.f / s0 : 0.f;
    float is1 = (deg > 0) ? 1.f / s1 : 0.f;

    float a0 = 0.f, a1 = 0.f;
    for (int j = 0; j < deg; ++j) {
        int eid = eidx[off + j];
        int sn = src[eid];
        float w0 = __expf(logit[(size_t)eid * 8 + h0] - m0) * is0;
        float w1 = __expf(logit[(size_t)eid * 8 + h1] - m1) * is1;
        a0 += w0 * vb[(size_t)sn * 128 + d0];
        a1 += w1 * vb[(size_t)sn * 128 + d1];
    }
    hagg[w][d0] = a0;
    hagg[w][d1] = a1;
    __syncthreads();

    float r0 = hb[d0], r1 = hb[d1];
    #pragma unroll 4
    for (int d = 0; d < 128; ++d) {
        float hv = hagg[w][d];
        r0 += hv * hpT[d * 128 + d0];
        r1 += hv * hpT[d * 128 + d1];
    }
    if (valid) {
        h_out[(size_t)node * 128 + d0] = r0;
        h_out[(size_t)node * 128 + d1] = r1;
    }
}

// ---------- launcher ----------

extern "C" void kernel_launch(void* const* d_in, const int* in_sizes, int n_in,
                              void* d_out, int out_size, void* d_ws, size_t ws_size,
                              hipStream_t stream)
{
    const float* h       = (const float*)d_in[0];
    const float* e       = (const float*)d_in[1];
    const int*   src     = (const int*)d_in[2];
    const int*   dst     = (const int*)d_in[3];
    const float* qkv_w   = (const float*)d_in[4];
    const float* qkv_b   = (const float*)d_in[5];
    const float* c_w     = (const float*)d_in[6];
    const float* c_b     = (const float*)d_in[7];
    const float* hproj_w = (const float*)d_in[8];
    const float* hproj_b = (const float*)d_in[9];
    const float* eproj_w = (const float*)d_in[10];
    const float* eproj_b = (const float*)d_in[11];

    const int N = in_sizes[0] / 128;
    const int E = in_sizes[1] / 128;

    float* h_out    = (float*)d_out;
    float* e_out    = h_out + (size_t)N * 128;
    float* mean_out = e_out + (size_t)E * 128;

    char* wp = (char*)d_ws;
    auto alloc = [&](size_t b) {
        void* p = (void*)wp;
        wp += (b + 255) & ~(size_t)255;
        return p;
    };
    float* qkvT   = (float*)alloc(sizeof(float) * 384 * 128);
    float* cT     = (float*)alloc(sizeof(float) * 128 * 128);
    float* epT    = (float*)alloc(sizeof(float) * 128 * 128);
    float* hpT    = (float*)alloc(sizeof(float) * 128 * 128);
    float* qb     = (float*)alloc(sizeof(float) * (size_t)N * 128);
    float* kbuf   = (float*)alloc(sizeof(float) * (size_t)N * 128);
    float* vbuf   = (float*)alloc(sizeof(float) * (size_t)N * 128);
    float* logit  = (float*)alloc(sizeof(float) * (size_t)E * 8);
    int*   counts = (int*)alloc(sizeof(int) * (N + 1));
    int*   offs   = (int*)alloc(sizeof(int) * (N + 1));
    int*   cursor = (int*)alloc(sizeof(int) * (N + 1));
    int*   eidx   = (int*)alloc(sizeof(int) * E);

    hipMemsetAsync(counts, 0, sizeof(int) * (N + 1), stream);

    transpose_k<<<(384 * 128 + 255) / 256, 256, 0, stream>>>(qkv_w, qkvT, 384, 128);
    transpose_k<<<(128 * 128 + 255) / 256, 256, 0, stream>>>(c_w, cT, 128, 128);
    transpose_k<<<(128 * 128 + 255) / 256, 256, 0, stream>>>(eproj_w, epT, 128, 128);
    transpose_k<<<(128 * 128 + 255) / 256, 256, 0, stream>>>(hproj_w, hpT, 128, 128);

    qkv_kernel<<<(N + TS - 1) / TS, 256, 0, stream>>>(h, qkvT, qkv_b, qb, kbuf, vbuf, N);

    hist_kernel<<<(E + 255) / 256, 256, 0, stream>>>(dst, counts, E);
    scan_kernel<<<1, 1024, 0, stream>>>(counts, offs, N);
    copy_kernel<<<(N + 255) / 256, 256, 0, stream>>>(offs, cursor, N);
    scatter_kernel<<<(E + 255) / 256, 256, 0, stream>>>(dst, cursor, eidx, E);

    edge_kernel<<<(E + TS - 1) / TS, 256, 0, stream>>>(e, src, dst, cT, c_b, epT, eproj_b,
                                                       qb, kbuf, e_out, mean_out, logit, E);

    node_kernel<<<(N + 3) / 4, 256, 0, stream>>>(offs, eidx, src, logit, vbuf, hpT,
                                                 hproj_b, h_out, N);
}

// Round 2
// 837.980 us; speedup vs baseline: 1.3991x; 1.3991x over previous
//
#include <hip/hip_runtime.h>
#include <cmath>

typedef __attribute__((ext_vector_type(8))) short bf16x8;
typedef __attribute__((ext_vector_type(4))) float f32x4;

#define TS 64
#define LSTR 132
#define ATTN_SCALE 0.25f

__device__ inline unsigned short f2bf(float x) {
    union { float f; unsigned u; } v; v.f = x;
    unsigned r = v.u + 0x7FFFu + ((v.u >> 16) & 1u);
    return (unsigned short)(r >> 16);
}

// ---------- small utility kernels ----------

__global__ __launch_bounds__(256) void transpose_k(const float* __restrict__ s,
                                                   float* __restrict__ d, int R, int C) {
    int idx = blockIdx.x * 256 + threadIdx.x;
    if (idx < R * C) {
        int r = idx / C, c = idx % C;
        d[c * R + r] = s[idx];
    }
}

__global__ __launch_bounds__(256) void hist_kernel(const int* __restrict__ dst,
                                                   int* __restrict__ counts, int E) {
    int i = blockIdx.x * 256 + threadIdx.x;
    if (i < E) atomicAdd(&counts[dst[i]], 1);
}

__global__ __launch_bounds__(1024) void scan_kernel(const int* __restrict__ counts,
                                                    int* __restrict__ offsets, int N) {
    __shared__ int buf[1024];
    __shared__ int carry;
    int t = threadIdx.x;
    if (t == 0) { carry = 0; offsets[0] = 0; }
    __syncthreads();
    for (int base = 0; base < N; base += 1024) {
        int i = base + t;
        int v = (i < N) ? counts[i] : 0;
        buf[t] = v;
        __syncthreads();
        for (int dshift = 1; dshift < 1024; dshift <<= 1) {
            int add = (t >= dshift) ? buf[t - dshift] : 0;
            __syncthreads();
            buf[t] += add;
            __syncthreads();
        }
        if (i < N) offsets[i + 1] = carry + buf[t];
        __syncthreads();
        if (t == 0) carry += buf[1023];
        __syncthreads();
    }
}

__global__ __launch_bounds__(256) void copy_kernel(const int* __restrict__ a,
                                                   int* __restrict__ b, int n) {
    int i = blockIdx.x * 256 + threadIdx.x;
    if (i < n) b[i] = a[i];
}

__global__ __launch_bounds__(256) void scatter_kernel(const int* __restrict__ dst,
                                                      int* __restrict__ cursor,
                                                      int* __restrict__ eidx, int E) {
    int i = blockIdx.x * 256 + threadIdx.x;
    if (i < E) {
        int p = atomicAdd(&cursor[dst[i]], 1);
        eidx[p] = i;
    }
}

// ---------- weight -> MFMA B-fragment (bf16, frag-linear) ----------
// W layout: W[col*128 + k]  (i.e. original w[out][in]).
// Fragment for (n,kk): lane l, elem j -> B[k = kk*32 + 8*(l>>4)+j][col = n*16 + (l&15)]
//                                      = W[col][k].
__global__ __launch_bounds__(256) void make_frag(const float* __restrict__ W,
                                                 short* __restrict__ out) {
    int id = blockIdx.x * 256 + threadIdx.x;   // 0..2047
    if (id >= 2048) return;
    int l = id & 63, t16 = id >> 6;
    int kk = t16 & 3, n = t16 >> 2;
    int col = n * 16 + (l & 15);
    int k0 = kk * 32 + (l >> 4) * 8;
    #pragma unroll
    for (int j = 0; j < 8; ++j)
        out[id * 8 + j] = (short)f2bf(W[col * 128 + k0 + j]);
}

// ---------- qkv projection (f32 VALU, unchanged) ----------

__global__ __launch_bounds__(256) void qkv_kernel(
    const float* __restrict__ h, const float* __restrict__ wT,
    const float* __restrict__ qkvb, float* __restrict__ qb,
    float* __restrict__ kb, float* __restrict__ vb, int N)
{
    __shared__ float tile[TS * LSTR];
    const int t = threadIdx.x;
    const int base = blockIdx.x * TS;
    for (int i = 0; i < 8; ++i) {
        int flat = i * 1024 + t * 4;
        int r = flat >> 7, k = flat & 127;
        float4 val = make_float4(0.f, 0.f, 0.f, 0.f);
        if (base + r < N) val = *reinterpret_cast<const float4*>(&h[(size_t)(base + r) * 128 + k]);
        *reinterpret_cast<float4*>(&tile[r * LSTR + k]) = val;
    }
    __syncthreads();
    const int tx = t & 15, ty = t >> 4;
    const int col = tx * 8, row0 = ty * 4;
    for (int ch = 0; ch < 3; ++ch) {
        float acc[4][8];
        #pragma unroll
        for (int i = 0; i < 4; ++i)
            #pragma unroll
            for (int j = 0; j < 8; ++j) acc[i][j] = 0.f;
        const float* wp = wT + ch * 128 + col;
        #pragma unroll 4
        for (int k = 0; k < 128; ++k) {
            float4 w0 = *reinterpret_cast<const float4*>(&wp[k * 384]);
            float4 w1 = *reinterpret_cast<const float4*>(&wp[k * 384 + 4]);
            float wv[8] = {w0.x, w0.y, w0.z, w0.w, w1.x, w1.y, w1.z, w1.w};
            float ev[4];
            #pragma unroll
            for (int i = 0; i < 4; ++i) ev[i] = tile[(row0 + i) * LSTR + k];
            #pragma unroll
            for (int i = 0; i < 4; ++i)
                #pragma unroll
                for (int j = 0; j < 8; ++j) acc[i][j] += ev[i] * wv[j];
        }
        float* out = (ch == 0) ? qb : (ch == 1) ? kb : vb;
        float4 b0 = *reinterpret_cast<const float4*>(&qkvb[ch * 128 + col]);
        float4 b1 = *reinterpret_cast<const float4*>(&qkvb[ch * 128 + col + 4]);
        #pragma unroll
        for (int i = 0; i < 4; ++i) {
            int r = base + row0 + i;
            if (r < N) {
                float4 o0 = make_float4(acc[i][0] + b0.x, acc[i][1] + b0.y,
                                        acc[i][2] + b0.z, acc[i][3] + b0.w);
                float4 o1 = make_float4(acc[i][4] + b1.x, acc[i][5] + b1.y,
                                        acc[i][6] + b1.z, acc[i][7] + b1.w);
                *reinterpret_cast<float4*>(&out[(size_t)r * 128 + col]) = o0;
                *reinterpret_cast<float4*>(&out[(size_t)r * 128 + col + 4]) = o1;
            }
        }
    }
}

// ---------- fused edge kernel (MFMA bf16) ----------
// Tile: 64 edges x 128 cols, 4 waves, wave w owns edges [w*16, w*16+16).
// GEMM1: c_pre = e @ c_w.T via mfma_16x16x32_bf16 (8 n-tiles x 4 k-steps).
// Epilogue: tanh, gather k[src]/q[dst], score f32 -> logit/mean, bf16 -> LDS.
// GEMM2: e_out = score @ eproj_w.T via mfma.
// LDS e-tile reused for score; per-wave row ownership => single barrier.

__global__ __launch_bounds__(256) void edge_mfma(
    const float* __restrict__ e, const int* __restrict__ src, const int* __restrict__ dst,
    const short* __restrict__ cfrag, const float* __restrict__ cbias,
    const short* __restrict__ efrag, const float* __restrict__ ebias,
    const float* __restrict__ qb, const float* __restrict__ kb,
    float* __restrict__ e_out, float* __restrict__ mean_out,
    float* __restrict__ logit, int E)
{
    __shared__ __align__(16) char lds[64 * 256];
    const int t = threadIdx.x;
    const int base = blockIdx.x * 64;

    // stage e tile (64 rows x 128 cols) as bf16, XOR-swizzled: byte ^= (row&15)<<4
    for (int i = 0; i < 8; ++i) {
        int flat = i * 1024 + t * 4;
        int r = flat >> 7, k = flat & 127;
        float4 v = make_float4(0.f, 0.f, 0.f, 0.f);
        if (base + r < E) v = *reinterpret_cast<const float4*>(&e[(size_t)(base + r) * 128 + k]);
        ushort4 b;
        b.x = f2bf(v.x); b.y = f2bf(v.y); b.z = f2bf(v.z); b.w = f2bf(v.w);
        *reinterpret_cast<ushort4*>(lds + r * 256 + ((k * 2) ^ ((r & 15) << 4))) = b;
    }
    __syncthreads();

    const int w = t >> 6, l = t & 63;
    const int lr = l & 15, lg = l >> 4;
    const int myrow = w * 16 + lr;          // A-frag row (myrow&15 == lr)
    const int rowbase = myrow * 256;
    const int swz = lr << 4;

    // GEMM1 A-fragments: k = kk*32 + lg*8 + {0..7} contiguous -> one b128 each
    bf16x8 afr[4];
    #pragma unroll
    for (int kk = 0; kk < 4; ++kk)
        afr[kk] = *reinterpret_cast<const bf16x8*>(lds + rowbase + ((kk * 64 + lg * 16) ^ swz));

    const bf16x8* cf = reinterpret_cast<const bf16x8*>(cfrag);
    f32x4 acc[8];
    #pragma unroll
    for (int n = 0; n < 8; ++n) acc[n] = (f32x4){0.f, 0.f, 0.f, 0.f};
    #pragma unroll
    for (int n = 0; n < 8; ++n) {
        #pragma unroll
        for (int kk = 0; kk < 4; ++kk)
            acc[n] = __builtin_amdgcn_mfma_f32_16x16x32_bf16(afr[kk], cf[(n * 4 + kk) * 64 + l],
                                                             acc[n], 0, 0, 0);
    }

    // C/D layout: col = n*16 + lr, row(edge) = lg*4 + reg  (within wave's 16 rows)
    int er[4], si[4], di[4];
    bool vld[4];
    #pragma unroll
    for (int reg = 0; reg < 4; ++reg) {
        int ei = base + w * 16 + lg * 4 + reg;
        vld[reg] = ei < E;
        int ce = vld[reg] ? ei : (E - 1);
        er[reg] = ei;
        si[reg] = src[ce];
        di[reg] = dst[ce];
    }

    float macc[4] = {0.f, 0.f, 0.f, 0.f};
    #pragma unroll
    for (int n = 0; n < 8; ++n) {
        const int col = n * 16 + lr;
        const float cb = cbias[col];
        float sc[4];
        #pragma unroll
        for (int reg = 0; reg < 4; ++reg) {
            float kv = kb[(size_t)si[reg] * 128 + col];
            float qv = qb[(size_t)di[reg] * 128 + col];
            float cc = tanhf(acc[n][reg] + cb);
            sc[reg] = cc * kv * qv;
            macc[reg] += sc[reg];
            int row = w * 16 + lg * 4 + reg;
            *reinterpret_cast<unsigned short*>(
                lds + row * 256 + ((col * 2) ^ ((row & 15) << 4))) = f2bf(sc[reg]);
        }
        // logit[edge][n]: reduce over the 16 lanes (lr) holding this head
        #pragma unroll
        for (int reg = 0; reg < 4; ++reg) {
            float p = sc[reg];
            p += __shfl_xor(p, 1);
            p += __shfl_xor(p, 2);
            p += __shfl_xor(p, 4);
            p += __shfl_xor(p, 8);
            if (lr == 0 && vld[reg]) logit[(size_t)er[reg] * 8 + n] = p * ATTN_SCALE;
        }
    }
    // mean over heads: d16 = lr
    #pragma unroll
    for (int reg = 0; reg < 4; ++reg)
        if (vld[reg]) mean_out[(size_t)er[reg] * 16 + lr] = macc[reg] * 0.125f;

    // GEMM2 A-fragments from score (same rows, same swizzle; within-wave RAW on LDS)
    bf16x8 afr2[4];
    #pragma unroll
    for (int kk = 0; kk < 4; ++kk)
        afr2[kk] = *reinterpret_cast<const bf16x8*>(lds + rowbase + ((kk * 64 + lg * 16) ^ swz));

    const bf16x8* ef = reinterpret_cast<const bf16x8*>(efrag);
    f32x4 acc2[8];
    #pragma unroll
    for (int n = 0; n < 8; ++n) acc2[n] = (f32x4){0.f, 0.f, 0.f, 0.f};
    #pragma unroll
    for (int n = 0; n < 8; ++n) {
        #pragma unroll
        for (int kk = 0; kk < 4; ++kk)
            acc2[n] = __builtin_amdgcn_mfma_f32_16x16x32_bf16(afr2[kk], ef[(n * 4 + kk) * 64 + l],
                                                              acc2[n], 0, 0, 0);
    }
    #pragma unroll
    for (int n = 0; n < 8; ++n) {
        const float eb = ebias[n * 16 + lr];
        #pragma unroll
        for (int reg = 0; reg < 4; ++reg)
            if (vld[reg]) e_out[(size_t)er[reg] * 128 + n * 16 + lr] = acc2[n][reg] + eb;
    }
}

// ---------- per-node softmax + aggregation + hproj ----------

__global__ __launch_bounds__(256) void node_kernel(
    const int* __restrict__ offsets, const int* __restrict__ eidx,
    const int* __restrict__ src, const float* __restrict__ logit,
    const float* __restrict__ vb, const float* __restrict__ hpT,
    const float* __restrict__ hb, float* __restrict__ h_out, int N)
{
    __shared__ float hagg[4][128];
    const int t = threadIdx.x;
    const int w = t >> 6, lane = t & 63;
    const int node = blockIdx.x * 4 + w;
    const bool valid = node < N;
    int off = 0, deg = 0;
    if (valid) { off = offsets[node]; deg = offsets[node + 1] - off; }

    const int head = lane & 7, g = lane >> 3;
    float mym = -3.0e38f;
    for (int j = g; j < deg; j += 8) {
        int eid = eidx[off + j];
        mym = fmaxf(mym, logit[(size_t)eid * 8 + head]);
    }
    mym = fmaxf(mym, __shfl_xor(mym, 8));
    mym = fmaxf(mym, __shfl_xor(mym, 16));
    mym = fmaxf(mym, __shfl_xor(mym, 32));
    float ss = 0.f;
    for (int j = g; j < deg; j += 8) {
        int eid = eidx[off + j];
        ss += __expf(logit[(size_t)eid * 8 + head] - mym);
    }
    ss += __shfl_xor(ss, 8);
    ss += __shfl_xor(ss, 16);
    ss += __shfl_xor(ss, 32);

    const int d0 = lane, d1 = lane + 64;
    const int h0 = lane >> 4, h1 = 4 + h0;
    float m0 = __shfl(mym, h0), m1 = __shfl(mym, h1);
    float s0 = __shfl(ss, h0), s1 = __shfl(ss, h1);
    float is0 = (deg > 0) ? 1.f / s0 : 0.f;
    float is1 = (deg > 0) ? 1.f / s1 : 0.f;

    float a0 = 0.f, a1 = 0.f;
    for (int j = 0; j < deg; ++j) {
        int eid = eidx[off + j];
        int sn = src[eid];
        float w0 = __expf(logit[(size_t)eid * 8 + h0] - m0) * is0;
        float w1 = __expf(logit[(size_t)eid * 8 + h1] - m1) * is1;
        a0 += w0 * vb[(size_t)sn * 128 + d0];
        a1 += w1 * vb[(size_t)sn * 128 + d1];
    }
    hagg[w][d0] = a0;
    hagg[w][d1] = a1;
    __syncthreads();

    float r0 = hb[d0], r1 = hb[d1];
    #pragma unroll 4
    for (int d = 0; d < 128; ++d) {
        float hv = hagg[w][d];
        r0 += hv * hpT[d * 128 + d0];
        r1 += hv * hpT[d * 128 + d1];
    }
    if (valid) {
        h_out[(size_t)node * 128 + d0] = r0;
        h_out[(size_t)node * 128 + d1] = r1;
    }
}

// ---------- launcher ----------

extern "C" void kernel_launch(void* const* d_in, const int* in_sizes, int n_in,
                              void* d_out, int out_size, void* d_ws, size_t ws_size,
                              hipStream_t stream)
{
    const float* h       = (const float*)d_in[0];
    const float* e       = (const float*)d_in[1];
    const int*   src     = (const int*)d_in[2];
    const int*   dst     = (const int*)d_in[3];
    const float* qkv_w   = (const float*)d_in[4];
    const float* qkv_b   = (const float*)d_in[5];
    const float* c_w     = (const float*)d_in[6];
    const float* c_b     = (const float*)d_in[7];
    const float* hproj_w = (const float*)d_in[8];
    const float* hproj_b = (const float*)d_in[9];
    const float* eproj_w = (const float*)d_in[10];
    const float* eproj_b = (const float*)d_in[11];

    const int N = in_sizes[0] / 128;
    const int E = in_sizes[1] / 128;

    float* h_out    = (float*)d_out;
    float* e_out    = h_out + (size_t)N * 128;
    float* mean_out = e_out + (size_t)E * 128;

    char* wp = (char*)d_ws;
    auto alloc = [&](size_t b) {
        void* p = (void*)wp;
        wp += (b + 255) & ~(size_t)255;
        return p;
    };
    float* qkvT   = (float*)alloc(sizeof(float) * 384 * 128);
    float* hpT    = (float*)alloc(sizeof(float) * 128 * 128);
    short* cfragb = (short*)alloc(sizeof(short) * 2048 * 8);
    short* efragb = (short*)alloc(sizeof(short) * 2048 * 8);
    float* qb     = (float*)alloc(sizeof(float) * (size_t)N * 128);
    float* kbuf   = (float*)alloc(sizeof(float) * (size_t)N * 128);
    float* vbuf   = (float*)alloc(sizeof(float) * (size_t)N * 128);
    float* logit  = (float*)alloc(sizeof(float) * (size_t)E * 8);
    int*   counts = (int*)alloc(sizeof(int) * (N + 1));
    int*   offs   = (int*)alloc(sizeof(int) * (N + 1));
    int*   cursor = (int*)alloc(sizeof(int) * (N + 1));
    int*   eidx   = (int*)alloc(sizeof(int) * E);

    hipMemsetAsync(counts, 0, sizeof(int) * (N + 1), stream);

    transpose_k<<<(384 * 128 + 255) / 256, 256, 0, stream>>>(qkv_w, qkvT, 384, 128);
    transpose_k<<<(128 * 128 + 255) / 256, 256, 0, stream>>>(hproj_w, hpT, 128, 128);
    make_frag<<<8, 256, 0, stream>>>(c_w, cfragb);
    make_frag<<<8, 256, 0, stream>>>(eproj_w, efragb);

    qkv_kernel<<<(N + TS - 1) / TS, 256, 0, stream>>>(h, qkvT, qkv_b, qb, kbuf, vbuf, N);

    hist_kernel<<<(E + 255) / 256, 256, 0, stream>>>(dst, counts, E);
    scan_kernel<<<1, 1024, 0, stream>>>(counts, offs, N);
    copy_kernel<<<(N + 255) / 256, 256, 0, stream>>>(offs, cursor, N);
    scatter_kernel<<<(E + 255) / 256, 256, 0, stream>>>(dst, cursor, eidx, E);

    edge_mfma<<<(E + 63) / 64, 256, 0, stream>>>(e, src, dst, cfragb, c_b, efragb, eproj_b,
                                                 qb, kbuf, e_out, mean_out, logit, E);

    node_kernel<<<(N + 3) / 4, 256, 0, stream>>>(offs, eidx, src, logit, vbuf, hpT,
                                                 hproj_b, h_out, N);
}

// Round 3
// 593.744 us; speedup vs baseline: 1.9747x; 1.4113x over previous
//
#include <hip/hip_runtime.h>
#include <cmath>

typedef __attribute__((ext_vector_type(8))) short bf16x8;
typedef __attribute__((ext_vector_type(4))) float f32x4;

#define ATTN_SCALE 0.25f

__device__ inline unsigned short f2bf(float x) {
    union { float f; unsigned u; } v; v.f = x;
    unsigned r = v.u + 0x7FFFu + ((v.u >> 16) & 1u);
    return (unsigned short)(r >> 16);
}
__device__ inline float bf2f(unsigned short u) {
    union { unsigned u; float f; } v; v.u = ((unsigned)u) << 16; return v.f;
}
__device__ inline float fast_tanh(float x) {
    float xc = fminf(fmaxf(x, -15.f), 15.f);
    float t = __expf(2.f * xc);
    return (t - 1.f) * __builtin_amdgcn_rcpf(t + 1.f);
}

// ---------- CSR build ----------

__global__ __launch_bounds__(256) void hist_kernel(const int* __restrict__ dst,
                                                   int* __restrict__ counts, int E) {
    int i = blockIdx.x * 256 + threadIdx.x;
    if (i < E) atomicAdd(&counts[dst[i]], 1);
}

// 3-phase exclusive scan of counts[N] -> offsets[N+1]
__global__ __launch_bounds__(256) void scan1(const int* __restrict__ counts,
                                             int* __restrict__ tmp, int* __restrict__ bsum, int N) {
    __shared__ int wsum[4];
    int b = blockIdx.x, t = threadIdx.x;
    int base = b * 1024 + t * 4;
    int v0 = (base + 0 < N) ? counts[base + 0] : 0;
    int v1 = (base + 1 < N) ? counts[base + 1] : 0;
    int v2 = (base + 2 < N) ? counts[base + 2] : 0;
    int v3 = (base + 3 < N) ? counts[base + 3] : 0;
    int p0 = v0, p1 = p0 + v1, p2 = p1 + v2, p3 = p2 + v3;
    int s = p3;
    int lane = t & 63, wid = t >> 6;
    int sc = s;
    #pragma unroll
    for (int d = 1; d < 64; d <<= 1) {
        int o = __shfl_up(sc, d);
        if (lane >= d) sc += o;
    }
    if (lane == 63) wsum[wid] = sc;
    __syncthreads();
    int wof = 0;
    #pragma unroll
    for (int i = 0; i < 4; ++i) if (i < wid) wof += wsum[i];
    int excl = wof + sc - s;
    if (base + 0 < N) tmp[base + 0] = excl + p0;
    if (base + 1 < N) tmp[base + 1] = excl + p1;
    if (base + 2 < N) tmp[base + 2] = excl + p2;
    if (base + 3 < N) tmp[base + 3] = excl + p3;
    if (t == 255) bsum[b] = wof + sc;
}

__global__ void scan2(int* __restrict__ bsum, int nb) {   // 1 block, 64 threads
    int t = threadIdx.x;
    int v = (t < nb) ? bsum[t] : 0;
    int sc = v;
    #pragma unroll
    for (int d = 1; d < 64; d <<= 1) {
        int o = __shfl_up(sc, d);
        if (t >= d) sc += o;
    }
    if (t < nb) bsum[t] = sc - v;
}

__global__ __launch_bounds__(256) void scan3(const int* __restrict__ tmp,
                                             const int* __restrict__ bsum,
                                             int* __restrict__ offsets, int N) {
    int i = blockIdx.x * 256 + threadIdx.x;
    if (i < N) offsets[i + 1] = tmp[i] + bsum[i >> 10];
    if (i == 0) offsets[0] = 0;
}

__global__ __launch_bounds__(256) void copy_kernel(const int* __restrict__ a,
                                                   int* __restrict__ b, int n) {
    int i = blockIdx.x * 256 + threadIdx.x;
    if (i < n) b[i] = a[i];
}

__global__ __launch_bounds__(256) void scatter_kernel(const int* __restrict__ dst,
                                                      int* __restrict__ cursor,
                                                      int* __restrict__ eidx, int E) {
    int i = blockIdx.x * 256 + threadIdx.x;
    if (i < E) {
        int p = atomicAdd(&cursor[dst[i]], 1);
        eidx[p] = i;
    }
}

// ---------- weight -> MFMA B-fragment (bf16, frag-linear) ----------
// W[col*128 + k] (= w[out][in]); frag for (n,kk): lane l elem j ->
// B[k = kk*32 + 8*(l>>4)+j][col = n*16 + (l&15)]
__global__ __launch_bounds__(256) void make_frag(const float* __restrict__ W,
                                                 short* __restrict__ out) {
    int id = blockIdx.x * 256 + threadIdx.x;   // 0..2047
    if (id >= 2048) return;
    int l = id & 63, t16 = id >> 6;
    int kk = t16 & 3, n = t16 >> 2;
    int col = n * 16 + (l & 15);
    int k0 = kk * 32 + (l >> 4) * 8;
    #pragma unroll
    for (int j = 0; j < 8; ++j)
        out[id * 8 + j] = (short)f2bf(W[col * 128 + k0 + j]);
}

// ---------- generic rows x 128 @ 128x128 MFMA GEMM (1..3 channels) ----------

__global__ __launch_bounds__(256) void gemm128(
    const float* __restrict__ X, const short* __restrict__ frag,
    const float* __restrict__ bias,
    float* __restrict__ Y0, float* __restrict__ Y1, float* __restrict__ Y2,
    int nch, int R)
{
    __shared__ __align__(16) char lds[64 * 256];
    const int t = threadIdx.x;
    const int base = blockIdx.x * 64;
    for (int i = 0; i < 8; ++i) {
        int flat = i * 1024 + t * 4;
        int r = flat >> 7, k = flat & 127;
        float4 v = make_float4(0.f, 0.f, 0.f, 0.f);
        if (base + r < R) v = *reinterpret_cast<const float4*>(&X[(size_t)(base + r) * 128 + k]);
        ushort4 b;
        b.x = f2bf(v.x); b.y = f2bf(v.y); b.z = f2bf(v.z); b.w = f2bf(v.w);
        *reinterpret_cast<ushort4*>(lds + r * 256 + ((k * 2) ^ ((r & 15) << 4))) = b;
    }
    __syncthreads();
    const int w = t >> 6, l = t & 63, lr = l & 15, lg = l >> 4;
    const int rowbase = (w * 16 + lr) * 256, swz = lr << 4;
    bf16x8 afr[4];
    #pragma unroll
    for (int kk = 0; kk < 4; ++kk)
        afr[kk] = *reinterpret_cast<const bf16x8*>(lds + rowbase + ((kk * 64 + lg * 16) ^ swz));
    for (int ch = 0; ch < nch; ++ch) {
        const bf16x8* bf = reinterpret_cast<const bf16x8*>(frag + ch * 2048 * 8);
        f32x4 acc[8];
        #pragma unroll
        for (int n = 0; n < 8; ++n) acc[n] = (f32x4){0.f, 0.f, 0.f, 0.f};
        #pragma unroll
        for (int n = 0; n < 8; ++n)
            #pragma unroll
            for (int kk = 0; kk < 4; ++kk)
                acc[n] = __builtin_amdgcn_mfma_f32_16x16x32_bf16(afr[kk], bf[(n * 4 + kk) * 64 + l],
                                                                 acc[n], 0, 0, 0);
        float* Y = (ch == 0) ? Y0 : (ch == 1) ? Y1 : Y2;
        #pragma unroll
        for (int n = 0; n < 8; ++n) {
            int col = n * 16 + lr;
            float bv = bias[ch * 128 + col];
            #pragma unroll
            for (int reg = 0; reg < 4; ++reg) {
                int r = base + w * 16 + lg * 4 + reg;
                if (r < R) Y[(size_t)r * 128 + col] = acc[n][reg] + bv;
            }
        }
    }
}

// ---------- fused edge kernel (MFMA bf16) ----------

__global__ __launch_bounds__(256) void edge_mfma(
    const float* __restrict__ e, const int* __restrict__ src, const int* __restrict__ dst,
    const short* __restrict__ cfrag, const float* __restrict__ cbias,
    const short* __restrict__ efrag, const float* __restrict__ ebias,
    const float* __restrict__ qb, const float* __restrict__ kb,
    float* __restrict__ e_out, float* __restrict__ mean_out,
    float* __restrict__ logit, int E)
{
    __shared__ __align__(16) char lds[64 * 256];
    const int t = threadIdx.x;
    const int base = blockIdx.x * 64;

    // stage e tile as bf16, swizzled: byte ^= (row&15)<<4
    for (int i = 0; i < 8; ++i) {
        int flat = i * 1024 + t * 4;
        int r = flat >> 7, k = flat & 127;
        float4 v = make_float4(0.f, 0.f, 0.f, 0.f);
        if (base + r < E) v = *reinterpret_cast<const float4*>(&e[(size_t)(base + r) * 128 + k]);
        ushort4 b;
        b.x = f2bf(v.x); b.y = f2bf(v.y); b.z = f2bf(v.z); b.w = f2bf(v.w);
        *reinterpret_cast<ushort4*>(lds + r * 256 + ((k * 2) ^ ((r & 15) << 4))) = b;
    }
    __syncthreads();

    const int w = t >> 6, l = t & 63;
    const int lr = l & 15, lg = l >> 4;
    const int rowbase = (w * 16 + lr) * 256;
    const int swz = lr << 4;

    bf16x8 afr[4];
    #pragma unroll
    for (int kk = 0; kk < 4; ++kk)
        afr[kk] = *reinterpret_cast<const bf16x8*>(lds + rowbase + ((kk * 64 + lg * 16) ^ swz));

    const bf16x8* cf = reinterpret_cast<const bf16x8*>(cfrag);
    f32x4 acc[8];
    #pragma unroll
    for (int n = 0; n < 8; ++n) acc[n] = (f32x4){0.f, 0.f, 0.f, 0.f};
    #pragma unroll
    for (int n = 0; n < 8; ++n)
        #pragma unroll
        for (int kk = 0; kk < 4; ++kk)
            acc[n] = __builtin_amdgcn_mfma_f32_16x16x32_bf16(afr[kk], cf[(n * 4 + kk) * 64 + l],
                                                             acc[n], 0, 0, 0);

    // per-reg edge ids
    int er[4], si[4], di[4];
    bool vld[4];
    #pragma unroll
    for (int reg = 0; reg < 4; ++reg) {
        int ei = base + w * 16 + lg * 4 + reg;
        vld[reg] = ei < E;
        int ce = vld[reg] ? ei : (E - 1);
        er[reg] = ei;
        si[reg] = src[ce];
        di[reg] = dst[ce];
    }

    // tanh -> score; write bf16 score to LDS; accumulate head-mean in f32
    float macc[4] = {0.f, 0.f, 0.f, 0.f};
    #pragma unroll
    for (int n = 0; n < 8; ++n) {
        const int col = n * 16 + lr;
        const float cb = cbias[col];
        #pragma unroll
        for (int reg = 0; reg < 4; ++reg) {
            float kv = kb[(size_t)si[reg] * 128 + col];
            float qv = qb[(size_t)di[reg] * 128 + col];
            float sc = fast_tanh(acc[n][reg] + cb) * kv * qv;
            macc[reg] += sc;
            int row = w * 16 + lg * 4 + reg;
            *reinterpret_cast<unsigned short*>(
                lds + row * 256 + ((col * 2) ^ ((row & 15) << 4))) = f2bf(sc);
        }
    }
    #pragma unroll
    for (int reg = 0; reg < 4; ++reg)
        if (vld[reg]) mean_out[(size_t)er[reg] * 16 + lr] = macc[reg] * 0.125f;

    // A-frags from score (same rows/swizzle; in-wave DS ordering)
    bf16x8 afr2[4];
    #pragma unroll
    for (int kk = 0; kk < 4; ++kk)
        afr2[kk] = *reinterpret_cast<const bf16x8*>(lds + rowbase + ((kk * 64 + lg * 16) ^ swz));

    // logit via MFMA with head-indicator B-frag: B[k][h] = (k>>4 == h)
    bf16x8 ind[4];
    #pragma unroll
    for (int kk = 0; kk < 4; ++kk)
        #pragma unroll
        for (int j = 0; j < 8; ++j)
            ind[kk][j] = ((kk * 32 + lg * 8 + j) >> 4 == lr) ? (short)0x3F80 : (short)0;
    f32x4 lac = (f32x4){0.f, 0.f, 0.f, 0.f};
    #pragma unroll
    for (int kk = 0; kk < 4; ++kk)
        lac = __builtin_amdgcn_mfma_f32_16x16x32_bf16(afr2[kk], ind[kk], lac, 0, 0, 0);
    if (lr < 8) {
        #pragma unroll
        for (int reg = 0; reg < 4; ++reg)
            if (vld[reg]) logit[(size_t)er[reg] * 8 + lr] = lac[reg] * ATTN_SCALE;
    }

    // GEMM2: e_out = score @ eproj_w.T
    const bf16x8* ef = reinterpret_cast<const bf16x8*>(efrag);
    f32x4 acc2[8];
    #pragma unroll
    for (int n = 0; n < 8; ++n) acc2[n] = (f32x4){0.f, 0.f, 0.f, 0.f};
    #pragma unroll
    for (int n = 0; n < 8; ++n)
        #pragma unroll
        for (int kk = 0; kk < 4; ++kk)
            acc2[n] = __builtin_amdgcn_mfma_f32_16x16x32_bf16(afr2[kk], ef[(n * 4 + kk) * 64 + l],
                                                              acc2[n], 0, 0, 0);

    // e_out roundtrip: bf16 -> LDS (score dead) -> coalesced float4 stores
    #pragma unroll
    for (int n = 0; n < 8; ++n) {
        const int col = n * 16 + lr;
        const float eb = ebias[col];
        #pragma unroll
        for (int reg = 0; reg < 4; ++reg) {
            int row = w * 16 + lg * 4 + reg;
            *reinterpret_cast<unsigned short*>(
                lds + row * 256 + ((col * 2) ^ ((row & 15) << 4))) = f2bf(acc2[n][reg] + eb);
        }
    }
    #pragma unroll
    for (int rh = 0; rh < 2; ++rh) {
        #pragma unroll
        for (int ih = 0; ih < 2; ++ih) {
            int row = w * 16 + (l >> 3) + 8 * rh;
            int col = (l & 7) * 8 + 64 * ih;
            bf16x8 sv = *reinterpret_cast<const bf16x8*>(
                lds + row * 256 + ((col * 2) ^ ((row & 15) << 4)));
            float4 o0, o1;
            o0.x = bf2f((unsigned short)sv[0]); o0.y = bf2f((unsigned short)sv[1]);
            o0.z = bf2f((unsigned short)sv[2]); o0.w = bf2f((unsigned short)sv[3]);
            o1.x = bf2f((unsigned short)sv[4]); o1.y = bf2f((unsigned short)sv[5]);
            o1.z = bf2f((unsigned short)sv[6]); o1.w = bf2f((unsigned short)sv[7]);
            if (base + row < E) {
                *reinterpret_cast<float4*>(&e_out[(size_t)(base + row) * 128 + col]) = o0;
                *reinterpret_cast<float4*>(&e_out[(size_t)(base + row) * 128 + col + 4]) = o1;
            }
        }
    }
}

// ---------- per-node softmax + aggregation (no hproj) ----------
// LDS-staged chunks: 8 exp per edge total; agg loop reads weights/src from LDS.

__global__ __launch_bounds__(256) void node_kernel(
    const int* __restrict__ offsets, const int* __restrict__ eidx,
    const int* __restrict__ src, const float* __restrict__ logit,
    const float* __restrict__ vb, float* __restrict__ hagg, int N)
{
    __shared__ int   ls_src[4][64];
    __shared__ float ls_l[4][64][8];
    const int t = threadIdx.x, w = t >> 6, lane = t & 63;
    const int node = blockIdx.x * 4 + w;
    int off = 0, deg = 0;
    if (node < N) { off = offsets[node]; deg = offsets[node + 1] - off; }

    const int h = lane & 7, g = lane >> 3;
    float m = -3.0e38f, s = 0.f;

    for (int c0 = 0; c0 < deg; c0 += 64) {
        int cnt = min(64, deg - c0);
        if (lane < cnt) {
            int eid = eidx[off + c0 + lane];
            ls_src[w][lane] = src[eid];
            float4 l0 = *reinterpret_cast<const float4*>(&logit[(size_t)eid * 8]);
            float4 l1 = *reinterpret_cast<const float4*>(&logit[(size_t)eid * 8 + 4]);
            *reinterpret_cast<float4*>(&ls_l[w][lane][0]) = l0;
            *reinterpret_cast<float4*>(&ls_l[w][lane][4]) = l1;
        }
        __asm__ __volatile__("s_waitcnt lgkmcnt(0)" ::: "memory");
        float cm = -3.0e38f;
        for (int j = g; j < cnt; j += 8) cm = fmaxf(cm, ls_l[w][j][h]);
        cm = fmaxf(cm, __shfl_xor(cm, 8));
        cm = fmaxf(cm, __shfl_xor(cm, 16));
        cm = fmaxf(cm, __shfl_xor(cm, 32));
        float mn = fmaxf(m, cm);
        float cs = 0.f;
        for (int j = g; j < cnt; j += 8) cs += __expf(ls_l[w][j][h] - mn);
        cs += __shfl_xor(cs, 8); cs += __shfl_xor(cs, 16); cs += __shfl_xor(cs, 32);
        s = s * __expf(m - mn) + cs;
        m = mn;
    }
    float inv = (deg > 0) ? 1.f / s : 0.f;

    float a0 = 0.f, a1 = 0.f;
    const int d0 = lane, d1 = lane + 64, h0 = lane >> 4, h1 = 4 + h0;
    for (int c0 = 0; c0 < deg; c0 += 64) {
        int cnt = min(64, deg - c0);
        if (deg > 64 && lane < cnt) {   // restage (rare; single-chunk keeps pass-1 data)
            int eid = eidx[off + c0 + lane];
            ls_src[w][lane] = src[eid];
            float4 l0 = *reinterpret_cast<const float4*>(&logit[(size_t)eid * 8]);
            float4 l1 = *reinterpret_cast<const float4*>(&logit[(size_t)eid * 8 + 4]);
            *reinterpret_cast<float4*>(&ls_l[w][lane][0]) = l0;
            *reinterpret_cast<float4*>(&ls_l[w][lane][4]) = l1;
        }
        __asm__ __volatile__("s_waitcnt lgkmcnt(0)" ::: "memory");
        for (int j = g; j < cnt; j += 8)
            ls_l[w][j][h] = __expf(ls_l[w][j][h] - m) * inv;
        __asm__ __volatile__("s_waitcnt lgkmcnt(0)" ::: "memory");
        for (int j = 0; j < cnt; ++j) {
            int sn = ls_src[w][j];
            float w0 = ls_l[w][j][h0], w1 = ls_l[w][j][h1];
            a0 += w0 * vb[(size_t)sn * 128 + d0];
            a1 += w1 * vb[(size_t)sn * 128 + d1];
        }
    }
    if (node < N) {
        hagg[(size_t)node * 128 + d0] = a0;
        hagg[(size_t)node * 128 + d1] = a1;
    }
}

// ---------- launcher ----------

extern "C" void kernel_launch(void* const* d_in, const int* in_sizes, int n_in,
                              void* d_out, int out_size, void* d_ws, size_t ws_size,
                              hipStream_t stream)
{
    const float* h       = (const float*)d_in[0];
    const float* e       = (const float*)d_in[1];
    const int*   src     = (const int*)d_in[2];
    const int*   dst     = (const int*)d_in[3];
    const float* qkv_w   = (const float*)d_in[4];
    const float* qkv_b   = (const float*)d_in[5];
    const float* c_w     = (const float*)d_in[6];
    const float* c_b     = (const float*)d_in[7];
    const float* hproj_w = (const float*)d_in[8];
    const float* hproj_b = (const float*)d_in[9];
    const float* eproj_w = (const float*)d_in[10];
    const float* eproj_b = (const float*)d_in[11];

    const int N = in_sizes[0] / 128;
    const int E = in_sizes[1] / 128;

    float* h_out    = (float*)d_out;
    float* e_out    = h_out + (size_t)N * 128;
    float* mean_out = e_out + (size_t)E * 128;

    char* wp = (char*)d_ws;
    auto alloc = [&](size_t b) {
        void* p = (void*)wp;
        wp += (b + 255) & ~(size_t)255;
        return p;
    };
    short* qkvfrag = (short*)alloc(sizeof(short) * 3 * 2048 * 8);
    short* cfragb  = (short*)alloc(sizeof(short) * 2048 * 8);
    short* efragb  = (short*)alloc(sizeof(short) * 2048 * 8);
    short* hpfrag  = (short*)alloc(sizeof(short) * 2048 * 8);
    float* qb      = (float*)alloc(sizeof(float) * (size_t)N * 128);   // aliased by hagg later
    float* kbuf    = (float*)alloc(sizeof(float) * (size_t)N * 128);
    float* vbuf    = (float*)alloc(sizeof(float) * (size_t)N * 128);
    float* logit   = (float*)alloc(sizeof(float) * (size_t)E * 8);
    int*   counts  = (int*)alloc(sizeof(int) * (N + 1));
    int*   offs    = (int*)alloc(sizeof(int) * (N + 1));
    int*   cursor  = (int*)alloc(sizeof(int) * (N + 1));
    int*   stmp    = (int*)alloc(sizeof(int) * (N + 1));
    int*   bsum    = (int*)alloc(sizeof(int) * 64);
    int*   eidx    = (int*)alloc(sizeof(int) * E);
    float* hagg    = qb;   // qb dead after edge_mfma

    hipMemsetAsync(counts, 0, sizeof(int) * (N + 1), stream);

    make_frag<<<8, 256, 0, stream>>>(qkv_w, qkvfrag);
    make_frag<<<8, 256, 0, stream>>>(qkv_w + 128 * 128, qkvfrag + 2048 * 8);
    make_frag<<<8, 256, 0, stream>>>(qkv_w + 2 * 128 * 128, qkvfrag + 2 * 2048 * 8);
    make_frag<<<8, 256, 0, stream>>>(c_w, cfragb);
    make_frag<<<8, 256, 0, stream>>>(eproj_w, efragb);
    make_frag<<<8, 256, 0, stream>>>(hproj_w, hpfrag);

    gemm128<<<(N + 63) / 64, 256, 0, stream>>>(h, qkvfrag, qkv_b, qb, kbuf, vbuf, 3, N);

    hist_kernel<<<(E + 255) / 256, 256, 0, stream>>>(dst, counts, E);
    int nb = (N + 1023) / 1024;
    scan1<<<nb, 256, 0, stream>>>(counts, stmp, bsum, N);
    scan2<<<1, 64, 0, stream>>>(bsum, nb);
    scan3<<<(N + 255) / 256, 256, 0, stream>>>(stmp, bsum, offs, N);
    copy_kernel<<<(N + 256) / 256, 256, 0, stream>>>(offs, cursor, N + 1);
    scatter_kernel<<<(E + 255) / 256, 256, 0, stream>>>(dst, cursor, eidx, E);

    edge_mfma<<<(E + 63) / 64, 256, 0, stream>>>(e, src, dst, cfragb, c_b, efragb, eproj_b,
                                                 qb, kbuf, e_out, mean_out, logit, E);

    node_kernel<<<(N + 3) / 4, 256, 0, stream>>>(offs, eidx, src, logit, vbuf, hagg, N);

    gemm128<<<(N + 63) / 64, 256, 0, stream>>>(hagg, hpfrag, hproj_b, h_out, h_out, h_out, 1, N);
}